// Round 4
// baseline (830.409 us; speedup 1.0000x reference)
//
#include <hip/hip_runtime.h>

#define NN 100000
#define NE 1600000
#define DF 128
#define DOUT 64
#define NG 128
#define NB 391    // ceil(NN/256)
#define BSH 6     // 64 nodes per bucket
#define NBUK ((NN + 63) >> BSH)   // 1563

typedef short short8 __attribute__((ext_vector_type(8)));
typedef float floatx4 __attribute__((ext_vector_type(4)));

__device__ __forceinline__ unsigned short f2bf(float f) {
    unsigned int b = __float_as_uint(f);
    unsigned int r = (b + 0x7fffu + ((b >> 16) & 1u)) >> 16;
    return (unsigned short)r;
}
__device__ __forceinline__ float bf2f_lo(unsigned int v) { return __uint_as_float(v << 16); }
__device__ __forceinline__ float bf2f_hi(unsigned int v) { return __uint_as_float(v & 0xffff0000u); }

// ---------------- graph preprocessing ----------------

__global__ void k_zero(int* __restrict__ cnt) {
    int i = blockIdx.x * blockDim.x + threadIdx.x;
    if (i < NN) cnt[i] = 0;
}

__global__ void k_hist(const int* __restrict__ dst, int* __restrict__ cnt) {
    int i = blockIdx.x * blockDim.x + threadIdx.x;
    if (i < NE) atomicAdd(&cnt[dst[i]], 1);
}

__global__ __launch_bounds__(256) void k_partial(const int* __restrict__ cnt,
                                                 int* __restrict__ bsum) {
    __shared__ int sh[256];
    int t = threadIdx.x;
    int idx = blockIdx.x * 256 + t;
    int v = (idx < NN) ? cnt[idx] : 0;
    sh[t] = v;
    __syncthreads();
    for (int off = 128; off > 0; off >>= 1) {
        if (t < off) sh[t] += sh[t + off];
        __syncthreads();
    }
    if (t == 0) bsum[blockIdx.x] = sh[0];
}

__global__ __launch_bounds__(512) void k_scansums(const int* __restrict__ bsum,
                                                  int* __restrict__ boff,
                                                  int* __restrict__ rowptr) {
    __shared__ int sh[512];
    int t = threadIdx.x;
    int v = (t < NB) ? bsum[t] : 0;
    sh[t] = v;
    __syncthreads();
    for (int off = 1; off < 512; off <<= 1) {
        int a = (t >= off) ? sh[t - off] : 0;
        __syncthreads();
        sh[t] += a;
        __syncthreads();
    }
    if (t < NB) boff[t] = sh[t] - v;
    if (t == 511) rowptr[NN] = sh[511];
}

__global__ __launch_bounds__(256) void k_write(const int* __restrict__ cnt,
                                               const int* __restrict__ boff,
                                               int* __restrict__ rowptr,
                                               float* __restrict__ dinv) {
    __shared__ int sh[256];
    int t = threadIdx.x;
    int idx = blockIdx.x * 256 + t;
    int v = (idx < NN) ? cnt[idx] : 0;
    sh[t] = v;
    __syncthreads();
    for (int off = 1; off < 256; off <<= 1) {
        int a = (t >= off) ? sh[t - off] : 0;
        __syncthreads();
        sh[t] += a;
        __syncthreads();
    }
    if (idx < NN) {
        rowptr[idx] = sh[t] - v + boff[blockIdx.x];
        dinv[idx] = rsqrtf((float)(v + 1));
    }
}

// bucket cursors = rowptr at bucket boundaries
__global__ void k_binit(const int* __restrict__ rowptr, int* __restrict__ bcur) {
    int b = blockIdx.x * blockDim.x + threadIdx.x;
    if (b < NBUK) bcur[b] = rowptr[b << BSH];
}

// pass A: bin (src,dst) pairs into CSR-aligned bucket regions
__global__ void k_bucket(const int* __restrict__ src, const int* __restrict__ dst,
                         int* __restrict__ bcur, int2* __restrict__ ebuf) {
    int i = blockIdx.x * blockDim.x + threadIdx.x;
    if (i < NE) {
        int s = src[i], d = dst[i];
        int p = atomicAdd(&bcur[d >> BSH], 1);
        ebuf[p] = make_int2(s, d);
    }
}

// pass B: place within bucket using LDS cursors
__global__ __launch_bounds__(256) void k_place(const int2* __restrict__ ebuf,
                                               const int* __restrict__ rowptr,
                                               int* __restrict__ col) {
    __shared__ int lcur[64];
    int b = blockIdx.x;
    int t = threadIdx.x;
    int n0 = b << BSH;
    int nend = min(n0 + 64, NN);
    if (t < 64) {
        int node = n0 + t;
        lcur[t] = (node < NN) ? rowptr[node] : 0;
    }
    __syncthreads();
    int e0 = rowptr[n0], e1 = rowptr[nend];
    for (int e = e0 + t; e < e1; e += 256) {
        int2 pr = ebuf[e];
        int p = atomicAdd(&lcur[pr.y - n0], 1);
        col[p] = pr.x;
    }
}

// ---------------- bf16 conversions ----------------

__global__ __launch_bounds__(256) void k_prepw(const float* __restrict__ W,
                                               unsigned short* __restrict__ Wb) {
    int idx = blockIdx.x * 256 + threadIdx.x;
    if (idx >= 2048) return;
    int l = idx & 63;
    int s = (idx >> 6) & 3;
    int t = idx >> 8;
    int k0 = s * 32 + (l >> 4) * 8;
    int c = t * 16 + (l & 15);
    unsigned short o[8];
#pragma unroll
    for (int j = 0; j < 8; j++) o[j] = f2bf(W[(k0 + j) * DF + c]);
    *(short8*)&Wb[idx * 8] = *(short8*)o;
}

__global__ __launch_bounds__(256) void k_prepx(const float* __restrict__ x,
                                               unsigned short* __restrict__ xb) {
    size_t i = ((size_t)blockIdx.x * 256 + threadIdx.x) * 8;
    if (i >= (size_t)NN * DF) return;
    float4 a = *(const float4*)&x[i];
    float4 b = *(const float4*)&x[i + 4];
    unsigned short o[8] = {f2bf(a.x), f2bf(a.y), f2bf(a.z), f2bf(a.w),
                           f2bf(b.x), f2bf(b.y), f2bf(b.z), f2bf(b.w)};
    *(short8*)&xb[i] = *(short8*)o;
}

// ---------------- per-layer compute ----------------

__global__ __launch_bounds__(256) void k_gemm(const unsigned short* __restrict__ X,
                                              const unsigned short* __restrict__ Wb,
                                              const float* __restrict__ dinv,
                                              unsigned short* __restrict__ hs) {
    int t = threadIdx.x;
    int wave = t >> 6, l = t & 63;
    int r0 = blockIdx.x * 64 + wave * 16;
    int lm = l & 15, q = l >> 4;

    int arow = r0 + lm;
    if (arow >= NN) arow = NN - 1;
    const unsigned short* xrow = X + (size_t)arow * DF + q * 8;
    short8 af0 = *(const short8*)(xrow);
    short8 af1 = *(const short8*)(xrow + 32);
    short8 af2 = *(const short8*)(xrow + 64);
    short8 af3 = *(const short8*)(xrow + 96);

    int orow = r0 + q * 4;
    float dv[4];
#pragma unroll
    for (int j = 0; j < 4; j++) dv[j] = (orow + j < NN) ? dinv[orow + j] : 0.f;

#pragma unroll
    for (int tt = 0; tt < 8; tt++) {
        floatx4 acc = {0.f, 0.f, 0.f, 0.f};
        const unsigned short* wp = Wb + ((size_t)(tt * 4) * 64 + l) * 8;
        acc = __builtin_amdgcn_mfma_f32_16x16x32_bf16(af0, *(const short8*)(wp), acc, 0, 0, 0);
        acc = __builtin_amdgcn_mfma_f32_16x16x32_bf16(af1, *(const short8*)(wp + 512), acc, 0, 0, 0);
        acc = __builtin_amdgcn_mfma_f32_16x16x32_bf16(af2, *(const short8*)(wp + 1024), acc, 0, 0, 0);
        acc = __builtin_amdgcn_mfma_f32_16x16x32_bf16(af3, *(const short8*)(wp + 1536), acc, 0, 0, 0);
        int c = tt * 16 + lm;
#pragma unroll
        for (int j = 0; j < 4; j++) {
            int r = orow + j;
            if (r < NN) hs[(size_t)r * DF + c] = f2bf(acc[j] * dv[j]);
        }
    }
}

__global__ __launch_bounds__(256) void k_agg(const unsigned short* __restrict__ hs,
                                             const int* __restrict__ rowptr,
                                             const int* __restrict__ col,
                                             const float* __restrict__ dinv,
                                             const float* __restrict__ b,
                                             unsigned short* __restrict__ out) {
    int n = (int)((blockIdx.x * (size_t)blockDim.x + threadIdx.x) >> 6);
    int lane = threadIdx.x & 63;
    if (n >= NN) return;
    int f = lane * 2;
    unsigned int sv = *(const unsigned int*)&hs[(size_t)n * DF + f];
    float ax = bf2f_lo(sv), ay = bf2f_hi(sv);
    int e = rowptr[n];
    int e1 = rowptr[n + 1];
    for (; e + 4 <= e1; e += 4) {
        int s0 = col[e], s1 = col[e + 1], s2 = col[e + 2], s3 = col[e + 3];
        unsigned int v0 = *(const unsigned int*)&hs[(size_t)s0 * DF + f];
        unsigned int v1 = *(const unsigned int*)&hs[(size_t)s1 * DF + f];
        unsigned int v2 = *(const unsigned int*)&hs[(size_t)s2 * DF + f];
        unsigned int v3 = *(const unsigned int*)&hs[(size_t)s3 * DF + f];
        ax += (bf2f_lo(v0) + bf2f_lo(v1)) + (bf2f_lo(v2) + bf2f_lo(v3));
        ay += (bf2f_hi(v0) + bf2f_hi(v1)) + (bf2f_hi(v2) + bf2f_hi(v3));
    }
    for (; e < e1; e++) {
        unsigned int v = *(const unsigned int*)&hs[(size_t)col[e] * DF + f];
        ax += bf2f_lo(v);
        ay += bf2f_hi(v);
    }
    float dvn = dinv[n];
    float2 bb = *(const float2*)&b[f];
    float ox = fmaxf(dvn * ax + bb.x, 0.f);
    float oy = fmaxf(dvn * ay + bb.y, 0.f);
    unsigned int packed = (unsigned int)f2bf(ox) | ((unsigned int)f2bf(oy) << 16);
    *(unsigned int*)&out[(size_t)n * DF + f] = packed;
}

// ---------------- pooling + FC ----------------

__global__ void k_bounds(const int* __restrict__ batch, int* __restrict__ gstart) {
    int g = threadIdx.x;
    if (g > NG) return;
    int lo = 0, hi = NN;
    while (lo < hi) {
        int mid = (lo + hi) >> 1;
        if (batch[mid] < g) lo = mid + 1; else hi = mid;
    }
    gstart[g] = lo;
}

__global__ __launch_bounds__(256) void k_pool(const unsigned short* __restrict__ h,
                                              const int* __restrict__ gstart,
                                              float* __restrict__ pooled) {
    __shared__ float red[256];
    int g = blockIdx.x;
    int t = threadIdx.x;
    int f = t & 127, half = t >> 7;
    int s = gstart[g], epos = gstart[g + 1];
    float acc = 0.f;
    for (int n = s + half; n < epos; n += 2)
        acc += __uint_as_float((unsigned int)h[(size_t)n * DF + f] << 16);
    red[t] = acc;
    __syncthreads();
    if (t < 128) {
        int c = epos - s;
        float tot = red[t] + red[t + 128];
        pooled[g * DF + f] = tot / (float)max(c, 1);
    }
}

__global__ __launch_bounds__(64) void k_fc(const float* __restrict__ pooled,
                                           const float* __restrict__ Wfc,
                                           const float* __restrict__ bfc,
                                           float* __restrict__ out) {
    int g = blockIdx.x;
    int o = threadIdx.x;
    float acc = bfc[o];
    for (int k = 0; k < DF; k++) acc += pooled[g * DF + k] * Wfc[k * DOUT + o];
    out[g * DOUT + o] = acc;
}

// ---------------- launch ----------------

extern "C" void kernel_launch(void* const* d_in, const int* in_sizes, int n_in,
                              void* d_out, int out_size, void* d_ws, size_t ws_size,
                              hipStream_t stream) {
    const float* x     = (const float*)d_in[0];
    const int*   ei    = (const int*)d_in[1];
    const int*   batch = (const int*)d_in[2];
    const float* W1 = (const float*)d_in[3];
    const float* b1 = (const float*)d_in[4];
    const float* W2 = (const float*)d_in[5];
    const float* b2 = (const float*)d_in[6];
    const float* W3 = (const float*)d_in[7];
    const float* b3 = (const float*)d_in[8];
    const float* Wfc = (const float*)d_in[9];
    const float* bfc = (const float*)d_in[10];
    float* out = (float*)d_out;

    char* p = (char*)d_ws;
    unsigned short* xb = (unsigned short*)p;  p += (size_t)NN * DF * sizeof(short);
    unsigned short* hs = (unsigned short*)p;  p += (size_t)NN * DF * sizeof(short);
    unsigned short* ob = (unsigned short*)p;  p += (size_t)NN * DF * sizeof(short);
    unsigned short* Wb1 = (unsigned short*)p; p += 16384 * sizeof(short);
    unsigned short* Wb2 = (unsigned short*)p; p += 16384 * sizeof(short);
    unsigned short* Wb3 = (unsigned short*)p; p += 16384 * sizeof(short);
    float* dinv = (float*)p;           p += (size_t)NN * sizeof(float);
    int* cnt    = (int*)p;             p += (size_t)NN * sizeof(int);
    int* rowptr = (int*)p;             p += (size_t)(NN + 4) * sizeof(int);
    int* col    = (int*)p;             p += (size_t)NE * sizeof(int);
    int2* ebuf  = (int2*)p;            p += (size_t)NE * sizeof(int2);
    int* bcur   = (int*)p;             p += (size_t)(NBUK + 4) * sizeof(int);
    int* gstart = (int*)p;             p += (size_t)(NG + 4) * sizeof(int);
    float* pooled = (float*)p;         p += (size_t)NG * DF * sizeof(float);
    int* bsum   = (int*)p;             p += (size_t)(NB + 4) * sizeof(int);
    int* boff   = (int*)p;             p += (size_t)(NB + 4) * sizeof(int);

    const int* e_src = ei;
    const int* e_dst = ei + NE;

    // graph preprocessing (CSR by dst, two-pass binning)
    k_zero<<<(NN + 255) / 256, 256, 0, stream>>>(cnt);
    k_hist<<<(NE + 255) / 256, 256, 0, stream>>>(e_dst, cnt);
    k_partial<<<NB, 256, 0, stream>>>(cnt, bsum);
    k_scansums<<<1, 512, 0, stream>>>(bsum, boff, rowptr);
    k_write<<<NB, 256, 0, stream>>>(cnt, boff, rowptr, dinv);
    k_binit<<<(NBUK + 255) / 256, 256, 0, stream>>>(rowptr, bcur);
    k_bucket<<<(NE + 255) / 256, 256, 0, stream>>>(e_src, e_dst, bcur, ebuf);
    k_place<<<NBUK, 256, 0, stream>>>(ebuf, rowptr, col);

    // bf16 conversions
    k_prepw<<<8, 256, 0, stream>>>(W1, Wb1);
    k_prepw<<<8, 256, 0, stream>>>(W2, Wb2);
    k_prepw<<<8, 256, 0, stream>>>(W3, Wb3);
    k_prepx<<<(NN * DF / 8 + 255) / 256, 256, 0, stream>>>(x, xb);

    int ggrid = (NN + 63) / 64;
    int agg_blocks = (NN + 3) / 4;

    // layer 1
    k_gemm<<<ggrid, 256, 0, stream>>>(xb, Wb1, dinv, hs);
    k_agg<<<agg_blocks, 256, 0, stream>>>(hs, rowptr, col, dinv, b1, ob);
    // layer 2
    k_gemm<<<ggrid, 256, 0, stream>>>(ob, Wb2, dinv, hs);
    k_agg<<<agg_blocks, 256, 0, stream>>>(hs, rowptr, col, dinv, b2, ob);
    // layer 3
    k_gemm<<<ggrid, 256, 0, stream>>>(ob, Wb3, dinv, hs);
    k_agg<<<agg_blocks, 256, 0, stream>>>(hs, rowptr, col, dinv, b3, ob);

    // pool + fc
    k_bounds<<<1, 256, 0, stream>>>(batch, gstart);
    k_pool<<<NG, 256, 0, stream>>>(ob, gstart, pooled);
    k_fc<<<NG, 64, 0, stream>>>(pooled, Wfc, bfc, out);
}

// Round 5
// 559.206 us; speedup vs baseline: 1.4850x; 1.4850x over previous
//
#include <hip/hip_runtime.h>

#define NN 100000
#define NE 1600000
#define DF 128
#define DOUT 64
#define NG 128
#define NB 391      // ceil(NN/256) buckets of 256 nodes
#define EPB 8192    // edges per block in binning passes
#define NBLKA ((NE + EPB - 1) / EPB)  // 196

typedef short short8 __attribute__((ext_vector_type(8)));
typedef float floatx4 __attribute__((ext_vector_type(4)));

__device__ __forceinline__ unsigned short f2bf(float f) {
    unsigned int b = __float_as_uint(f);
    unsigned int r = (b + 0x7fffu + ((b >> 16) & 1u)) >> 16;
    return (unsigned short)r;
}
__device__ __forceinline__ float bf2f_lo(unsigned int v) { return __uint_as_float(v << 16); }
__device__ __forceinline__ float bf2f_hi(unsigned int v) { return __uint_as_float(v & 0xffff0000u); }

// ---------------- CSR build: LDS-binned radix partition ----------------

__global__ void k_zerob(int* __restrict__ b) {
    int i = blockIdx.x * blockDim.x + threadIdx.x;
    if (i < NB) b[i] = 0;
}

// per-block LDS histogram of dst>>8, one flush per bucket per block
__global__ __launch_bounds__(256) void k_bcount(const int* __restrict__ dst,
                                                int* __restrict__ bhist) {
    __shared__ int lh[NB];
    int t = threadIdx.x;
    for (int i = t; i < NB; i += 256) lh[i] = 0;
    __syncthreads();
    int e0 = blockIdx.x * EPB;
    int e1 = min(e0 + EPB, NE);
    for (int e = e0 + t; e < e1; e += 256) atomicAdd(&lh[dst[e] >> 8], 1);
    __syncthreads();
    for (int i = t; i < NB; i += 256) {
        int c = lh[i];
        if (c) atomicAdd(&bhist[i], c);
    }
}

// scan bucket totals -> bbase (exclusive, +sentinel), init bcur
__global__ __launch_bounds__(512) void k_bscan(const int* __restrict__ bhist,
                                               int* __restrict__ bbase,
                                               int* __restrict__ bcur) {
    __shared__ int sh[512];
    int t = threadIdx.x;
    int v = (t < NB) ? bhist[t] : 0;
    sh[t] = v;
    __syncthreads();
    for (int off = 1; off < 512; off <<= 1) {
        int a = (t >= off) ? sh[t - off] : 0;
        __syncthreads();
        sh[t] += a;
        __syncthreads();
    }
    if (t < NB) {
        bbase[t] = sh[t] - v;
        bcur[t] = sh[t] - v;
    }
    if (t == NB - 1) bbase[NB] = sh[t];
}

// bin (src,dst) pairs: block-local hist -> one reservation atomic per bucket,
// pairs land in contiguous per-(block,bucket) runs
__global__ __launch_bounds__(256) void k_pairs(const int* __restrict__ src,
                                               const int* __restrict__ dst,
                                               int* __restrict__ bcur,
                                               int2* __restrict__ ebuf) {
    __shared__ int lh[NB];
    __shared__ int lbase[NB];
    int t = threadIdx.x;
    for (int i = t; i < NB; i += 256) lh[i] = 0;
    __syncthreads();
    int e0 = blockIdx.x * EPB;
    int e1 = min(e0 + EPB, NE);
    for (int e = e0 + t; e < e1; e += 256) atomicAdd(&lh[dst[e] >> 8], 1);
    __syncthreads();
    for (int i = t; i < NB; i += 256) {
        int c = lh[i];
        lbase[i] = c ? atomicAdd(&bcur[i], c) : 0;
    }
    __syncthreads();
    for (int i = t; i < NB; i += 256) lh[i] = 0;
    __syncthreads();
    for (int e = e0 + t; e < e1; e += 256) {
        int s = src[e], d = dst[e];
        int bk = d >> 8;
        int off = atomicAdd(&lh[bk], 1);
        ebuf[lbase[bk] + off] = make_int2(s, d);
    }
}

// one block per bucket (256 nodes): LDS degree count + scan + LDS-cursor place.
// emits rowptr (canonical CSR order), dinv, col. no global atomics.
__global__ __launch_bounds__(256) void k_build(const int2* __restrict__ ebuf,
                                               const int* __restrict__ bbase,
                                               int* __restrict__ rowptr,
                                               float* __restrict__ dinv,
                                               int* __restrict__ col) {
    __shared__ int deg[256];
    __shared__ int lst[256];
    int b = blockIdx.x, t = threadIdx.x;
    int n0 = b << 8;
    int node = n0 + t;
    deg[t] = 0;
    __syncthreads();
    int e0 = bbase[b], e1 = bbase[b + 1];
    for (int e = e0 + t; e < e1; e += 256) atomicAdd(&deg[ebuf[e].y - n0], 1);
    __syncthreads();
    int v = deg[t];
    lst[t] = v;
    __syncthreads();
    for (int off = 1; off < 256; off <<= 1) {
        int a = (t >= off) ? lst[t - off] : 0;
        __syncthreads();
        lst[t] += a;
        __syncthreads();
    }
    int mystart = e0 + lst[t] - v;
    if (node < NN) {
        rowptr[node] = mystart;
        dinv[node] = rsqrtf((float)(v + 1));  // +1 self-loop
    }
    if (b == NB - 1 && t == 255) rowptr[NN] = e1;
    lst[t] = mystart;  // reuse as cursor
    __syncthreads();
    for (int e = e0 + t; e < e1; e += 256) {
        int2 pr = ebuf[e];
        int p = atomicAdd(&lst[pr.y - n0], 1);
        col[p] = pr.x;
    }
}

// ---------------- bf16 conversions ----------------

__global__ __launch_bounds__(256) void k_prepw(const float* __restrict__ W,
                                               unsigned short* __restrict__ Wb) {
    int idx = blockIdx.x * 256 + threadIdx.x;
    if (idx >= 2048) return;
    int l = idx & 63;
    int s = (idx >> 6) & 3;
    int t = idx >> 8;
    int k0 = s * 32 + (l >> 4) * 8;
    int c = t * 16 + (l & 15);
    unsigned short o[8];
#pragma unroll
    for (int j = 0; j < 8; j++) o[j] = f2bf(W[(k0 + j) * DF + c]);
    *(short8*)&Wb[idx * 8] = *(short8*)o;
}

__global__ __launch_bounds__(256) void k_prepx(const float* __restrict__ x,
                                               unsigned short* __restrict__ xb) {
    size_t i = ((size_t)blockIdx.x * 256 + threadIdx.x) * 8;
    if (i >= (size_t)NN * DF) return;
    float4 a = *(const float4*)&x[i];
    float4 b = *(const float4*)&x[i + 4];
    unsigned short o[8] = {f2bf(a.x), f2bf(a.y), f2bf(a.z), f2bf(a.w),
                           f2bf(b.x), f2bf(b.y), f2bf(b.z), f2bf(b.w)};
    *(short8*)&xb[i] = *(short8*)o;
}

// ---------------- per-layer compute ----------------

__global__ __launch_bounds__(256) void k_gemm(const unsigned short* __restrict__ X,
                                              const unsigned short* __restrict__ Wb,
                                              const float* __restrict__ dinv,
                                              unsigned short* __restrict__ hs) {
    int t = threadIdx.x;
    int wave = t >> 6, l = t & 63;
    int r0 = blockIdx.x * 64 + wave * 16;
    int lm = l & 15, q = l >> 4;

    int arow = r0 + lm;
    if (arow >= NN) arow = NN - 1;
    const unsigned short* xrow = X + (size_t)arow * DF + q * 8;
    short8 af0 = *(const short8*)(xrow);
    short8 af1 = *(const short8*)(xrow + 32);
    short8 af2 = *(const short8*)(xrow + 64);
    short8 af3 = *(const short8*)(xrow + 96);

    int orow = r0 + q * 4;
    float dv[4];
#pragma unroll
    for (int j = 0; j < 4; j++) dv[j] = (orow + j < NN) ? dinv[orow + j] : 0.f;

#pragma unroll
    for (int tt = 0; tt < 8; tt++) {
        floatx4 acc = {0.f, 0.f, 0.f, 0.f};
        const unsigned short* wp = Wb + ((size_t)(tt * 4) * 64 + l) * 8;
        acc = __builtin_amdgcn_mfma_f32_16x16x32_bf16(af0, *(const short8*)(wp), acc, 0, 0, 0);
        acc = __builtin_amdgcn_mfma_f32_16x16x32_bf16(af1, *(const short8*)(wp + 512), acc, 0, 0, 0);
        acc = __builtin_amdgcn_mfma_f32_16x16x32_bf16(af2, *(const short8*)(wp + 1024), acc, 0, 0, 0);
        acc = __builtin_amdgcn_mfma_f32_16x16x32_bf16(af3, *(const short8*)(wp + 1536), acc, 0, 0, 0);
        int c = tt * 16 + lm;
#pragma unroll
        for (int j = 0; j < 4; j++) {
            int r = orow + j;
            if (r < NN) hs[(size_t)r * DF + c] = f2bf(acc[j] * dv[j]);
        }
    }
}

__global__ __launch_bounds__(256) void k_agg(const unsigned short* __restrict__ hs,
                                             const int* __restrict__ rowptr,
                                             const int* __restrict__ col,
                                             const float* __restrict__ dinv,
                                             const float* __restrict__ b,
                                             unsigned short* __restrict__ out) {
    int n = (int)((blockIdx.x * (size_t)blockDim.x + threadIdx.x) >> 6);
    int lane = threadIdx.x & 63;
    if (n >= NN) return;
    int f = lane * 2;
    unsigned int sv = *(const unsigned int*)&hs[(size_t)n * DF + f];
    float ax = bf2f_lo(sv), ay = bf2f_hi(sv);
    int e = rowptr[n];
    int e1 = rowptr[n + 1];
    for (; e + 4 <= e1; e += 4) {
        int s0 = col[e], s1 = col[e + 1], s2 = col[e + 2], s3 = col[e + 3];
        unsigned int v0 = *(const unsigned int*)&hs[(size_t)s0 * DF + f];
        unsigned int v1 = *(const unsigned int*)&hs[(size_t)s1 * DF + f];
        unsigned int v2 = *(const unsigned int*)&hs[(size_t)s2 * DF + f];
        unsigned int v3 = *(const unsigned int*)&hs[(size_t)s3 * DF + f];
        ax += (bf2f_lo(v0) + bf2f_lo(v1)) + (bf2f_lo(v2) + bf2f_lo(v3));
        ay += (bf2f_hi(v0) + bf2f_hi(v1)) + (bf2f_hi(v2) + bf2f_hi(v3));
    }
    for (; e < e1; e++) {
        unsigned int v = *(const unsigned int*)&hs[(size_t)col[e] * DF + f];
        ax += bf2f_lo(v);
        ay += bf2f_hi(v);
    }
    float dvn = dinv[n];
    float2 bb = *(const float2*)&b[f];
    float ox = fmaxf(dvn * ax + bb.x, 0.f);
    float oy = fmaxf(dvn * ay + bb.y, 0.f);
    unsigned int packed = (unsigned int)f2bf(ox) | ((unsigned int)f2bf(oy) << 16);
    *(unsigned int*)&out[(size_t)n * DF + f] = packed;
}

// ---------------- pooling + FC ----------------

__global__ void k_bounds(const int* __restrict__ batch, int* __restrict__ gstart) {
    int g = threadIdx.x;
    if (g > NG) return;
    int lo = 0, hi = NN;
    while (lo < hi) {
        int mid = (lo + hi) >> 1;
        if (batch[mid] < g) lo = mid + 1; else hi = mid;
    }
    gstart[g] = lo;
}

__global__ __launch_bounds__(256) void k_pool(const unsigned short* __restrict__ h,
                                              const int* __restrict__ gstart,
                                              float* __restrict__ pooled) {
    __shared__ float red[256];
    int g = blockIdx.x;
    int t = threadIdx.x;
    int f = t & 127, half = t >> 7;
    int s = gstart[g], epos = gstart[g + 1];
    float acc = 0.f;
    for (int n = s + half; n < epos; n += 2)
        acc += __uint_as_float((unsigned int)h[(size_t)n * DF + f] << 16);
    red[t] = acc;
    __syncthreads();
    if (t < 128) {
        int c = epos - s;
        float tot = red[t] + red[t + 128];
        pooled[g * DF + f] = tot / (float)max(c, 1);
    }
}

__global__ __launch_bounds__(64) void k_fc(const float* __restrict__ pooled,
                                           const float* __restrict__ Wfc,
                                           const float* __restrict__ bfc,
                                           float* __restrict__ out) {
    int g = blockIdx.x;
    int o = threadIdx.x;
    float acc = bfc[o];
    for (int k = 0; k < DF; k++) acc += pooled[g * DF + k] * Wfc[k * DOUT + o];
    out[g * DOUT + o] = acc;
}

// ---------------- launch ----------------

extern "C" void kernel_launch(void* const* d_in, const int* in_sizes, int n_in,
                              void* d_out, int out_size, void* d_ws, size_t ws_size,
                              hipStream_t stream) {
    const float* x     = (const float*)d_in[0];
    const int*   ei    = (const int*)d_in[1];
    const int*   batch = (const int*)d_in[2];
    const float* W1 = (const float*)d_in[3];
    const float* b1 = (const float*)d_in[4];
    const float* W2 = (const float*)d_in[5];
    const float* b2 = (const float*)d_in[6];
    const float* W3 = (const float*)d_in[7];
    const float* b3 = (const float*)d_in[8];
    const float* Wfc = (const float*)d_in[9];
    const float* bfc = (const float*)d_in[10];
    float* out = (float*)d_out;

    char* p = (char*)d_ws;
    unsigned short* xb = (unsigned short*)p;  p += (size_t)NN * DF * sizeof(short);
    unsigned short* hs = (unsigned short*)p;  p += (size_t)NN * DF * sizeof(short);
    unsigned short* ob = (unsigned short*)p;  p += (size_t)NN * DF * sizeof(short);
    unsigned short* Wb1 = (unsigned short*)p; p += 16384 * sizeof(short);
    unsigned short* Wb2 = (unsigned short*)p; p += 16384 * sizeof(short);
    unsigned short* Wb3 = (unsigned short*)p; p += 16384 * sizeof(short);
    float* dinv = (float*)p;           p += (size_t)NN * sizeof(float);
    int* rowptr = (int*)p;             p += (size_t)(NN + 4) * sizeof(int);
    int* col    = (int*)p;             p += (size_t)NE * sizeof(int);
    int2* ebuf  = (int2*)p;            p += (size_t)NE * sizeof(int2);
    int* bhist  = (int*)p;             p += (size_t)(NB + 4) * sizeof(int);
    int* bbase  = (int*)p;             p += (size_t)(NB + 4) * sizeof(int);
    int* bcur   = (int*)p;             p += (size_t)(NB + 4) * sizeof(int);
    int* gstart = (int*)p;             p += (size_t)(NG + 4) * sizeof(int);
    float* pooled = (float*)p;         p += (size_t)NG * DF * sizeof(float);

    const int* e_src = ei;
    const int* e_dst = ei + NE;

    // CSR build (LDS-binned radix partition, 256 nodes/bucket)
    k_zerob<<<(NB + 255) / 256, 256, 0, stream>>>(bhist);
    k_bcount<<<NBLKA, 256, 0, stream>>>(e_dst, bhist);
    k_bscan<<<1, 512, 0, stream>>>(bhist, bbase, bcur);
    k_pairs<<<NBLKA, 256, 0, stream>>>(e_src, e_dst, bcur, ebuf);
    k_build<<<NB, 256, 0, stream>>>(ebuf, bbase, rowptr, dinv, col);

    // bf16 conversions
    k_prepw<<<8, 256, 0, stream>>>(W1, Wb1);
    k_prepw<<<8, 256, 0, stream>>>(W2, Wb2);
    k_prepw<<<8, 256, 0, stream>>>(W3, Wb3);
    k_prepx<<<(NN * DF / 8 + 255) / 256, 256, 0, stream>>>(x, xb);

    int ggrid = (NN + 63) / 64;
    int agg_blocks = (NN + 3) / 4;

    // layer 1
    k_gemm<<<ggrid, 256, 0, stream>>>(xb, Wb1, dinv, hs);
    k_agg<<<agg_blocks, 256, 0, stream>>>(hs, rowptr, col, dinv, b1, ob);
    // layer 2
    k_gemm<<<ggrid, 256, 0, stream>>>(ob, Wb2, dinv, hs);
    k_agg<<<agg_blocks, 256, 0, stream>>>(hs, rowptr, col, dinv, b2, ob);
    // layer 3
    k_gemm<<<ggrid, 256, 0, stream>>>(ob, Wb3, dinv, hs);
    k_agg<<<agg_blocks, 256, 0, stream>>>(hs, rowptr, col, dinv, b3, ob);

    // pool + fc
    k_bounds<<<1, 256, 0, stream>>>(batch, gstart);
    k_pool<<<NG, 256, 0, stream>>>(ob, gstart, pooled);
    k_fc<<<NG, 64, 0, stream>>>(pooled, Wfc, bfc, out);
}

// Round 6
// 466.303 us; speedup vs baseline: 1.7808x; 1.1992x over previous
//
#include <hip/hip_runtime.h>

#define NN 100000
#define NE 1600000
#define DF 128
#define DOUT 64
#define NG 128
#define NB 391      // ceil(NN/256) buckets of 256 nodes
#define EPB 8192    // edges per block in binning passes
#define NBLKA ((NE + EPB - 1) / EPB)  // 196
#define PCH 8       // pool chunks per graph

typedef short short8 __attribute__((ext_vector_type(8)));
typedef float floatx4 __attribute__((ext_vector_type(4)));

__device__ __forceinline__ unsigned short f2bf(float f) {
    unsigned int b = __float_as_uint(f);
    unsigned int r = (b + 0x7fffu + ((b >> 16) & 1u)) >> 16;
    return (unsigned short)r;
}
__device__ __forceinline__ float bf2f_lo(unsigned int v) { return __uint_as_float(v << 16); }
__device__ __forceinline__ float bf2f_hi(unsigned int v) { return __uint_as_float(v & 0xffff0000u); }

// ---------------- CSR build: LDS-binned radix partition ----------------

__global__ void k_zerob(int* __restrict__ b) {
    int i = blockIdx.x * blockDim.x + threadIdx.x;
    if (i < NB) b[i] = 0;
}

__global__ __launch_bounds__(256) void k_bcount(const int* __restrict__ dst,
                                                int* __restrict__ bhist) {
    __shared__ int lh[NB];
    int t = threadIdx.x;
    for (int i = t; i < NB; i += 256) lh[i] = 0;
    __syncthreads();
    int e0 = blockIdx.x * EPB;
    int e1 = min(e0 + EPB, NE);
    for (int e = e0 + t; e < e1; e += 256) atomicAdd(&lh[dst[e] >> 8], 1);
    __syncthreads();
    for (int i = t; i < NB; i += 256) {
        int c = lh[i];
        if (c) atomicAdd(&bhist[i], c);
    }
}

__global__ __launch_bounds__(512) void k_bscan(const int* __restrict__ bhist,
                                               int* __restrict__ bbase,
                                               int* __restrict__ bcur) {
    __shared__ int sh[512];
    int t = threadIdx.x;
    int v = (t < NB) ? bhist[t] : 0;
    sh[t] = v;
    __syncthreads();
    for (int off = 1; off < 512; off <<= 1) {
        int a = (t >= off) ? sh[t - off] : 0;
        __syncthreads();
        sh[t] += a;
        __syncthreads();
    }
    if (t < NB) {
        bbase[t] = sh[t] - v;
        bcur[t] = sh[t] - v;
    }
    if (t == NB - 1) bbase[NB] = sh[t];
}

__global__ __launch_bounds__(256) void k_pairs(const int* __restrict__ src,
                                               const int* __restrict__ dst,
                                               int* __restrict__ bcur,
                                               int2* __restrict__ ebuf) {
    __shared__ int lh[NB];
    __shared__ int lbase[NB];
    int t = threadIdx.x;
    for (int i = t; i < NB; i += 256) lh[i] = 0;
    __syncthreads();
    int e0 = blockIdx.x * EPB;
    int e1 = min(e0 + EPB, NE);
    for (int e = e0 + t; e < e1; e += 256) atomicAdd(&lh[dst[e] >> 8], 1);
    __syncthreads();
    for (int i = t; i < NB; i += 256) {
        int c = lh[i];
        lbase[i] = c ? atomicAdd(&bcur[i], c) : 0;
    }
    __syncthreads();
    for (int i = t; i < NB; i += 256) lh[i] = 0;
    __syncthreads();
    for (int e = e0 + t; e < e1; e += 256) {
        int s = src[e], d = dst[e];
        int bk = d >> 8;
        int off = atomicAdd(&lh[bk], 1);
        ebuf[lbase[bk] + off] = make_int2(s, d);
    }
}

__global__ __launch_bounds__(256) void k_build(const int2* __restrict__ ebuf,
                                               const int* __restrict__ bbase,
                                               int* __restrict__ rowptr,
                                               float* __restrict__ dinv,
                                               int* __restrict__ col) {
    __shared__ int deg[256];
    __shared__ int lst[256];
    int b = blockIdx.x, t = threadIdx.x;
    int n0 = b << 8;
    int node = n0 + t;
    deg[t] = 0;
    __syncthreads();
    int e0 = bbase[b], e1 = bbase[b + 1];
    for (int e = e0 + t; e < e1; e += 256) atomicAdd(&deg[ebuf[e].y - n0], 1);
    __syncthreads();
    int v = deg[t];
    lst[t] = v;
    __syncthreads();
    for (int off = 1; off < 256; off <<= 1) {
        int a = (t >= off) ? lst[t - off] : 0;
        __syncthreads();
        lst[t] += a;
        __syncthreads();
    }
    int mystart = e0 + lst[t] - v;
    if (node < NN) {
        rowptr[node] = mystart;
        dinv[node] = rsqrtf((float)(v + 1));  // +1 self-loop
    }
    if (b == NB - 1 && t == 255) rowptr[NN] = e1;
    lst[t] = mystart;
    __syncthreads();
    for (int e = e0 + t; e < e1; e += 256) {
        int2 pr = ebuf[e];
        int p = atomicAdd(&lst[pr.y - n0], 1);
        col[p] = pr.x;
    }
}

// ---------------- bf16 conversions ----------------

__global__ __launch_bounds__(256) void k_prepw(const float* __restrict__ W,
                                               unsigned short* __restrict__ Wb) {
    int idx = blockIdx.x * 256 + threadIdx.x;
    if (idx >= 2048) return;
    int l = idx & 63;
    int s = (idx >> 6) & 3;
    int t = idx >> 8;
    int k0 = s * 32 + (l >> 4) * 8;
    int c = t * 16 + (l & 15);
    unsigned short o[8];
#pragma unroll
    for (int j = 0; j < 8; j++) o[j] = f2bf(W[(k0 + j) * DF + c]);
    *(short8*)&Wb[idx * 8] = *(short8*)o;
}

__global__ __launch_bounds__(256) void k_prepx(const float* __restrict__ x,
                                               unsigned short* __restrict__ xb) {
    size_t i = ((size_t)blockIdx.x * 256 + threadIdx.x) * 8;
    if (i >= (size_t)NN * DF) return;
    float4 a = *(const float4*)&x[i];
    float4 b = *(const float4*)&x[i + 4];
    unsigned short o[8] = {f2bf(a.x), f2bf(a.y), f2bf(a.z), f2bf(a.w),
                           f2bf(b.x), f2bf(b.y), f2bf(b.z), f2bf(b.w)};
    *(short8*)&xb[i] = *(short8*)o;
}

// ---------------- per-layer compute ----------------

__global__ __launch_bounds__(256) void k_gemm(const unsigned short* __restrict__ X,
                                              const unsigned short* __restrict__ Wb,
                                              const float* __restrict__ dinv,
                                              unsigned short* __restrict__ hs) {
    int t = threadIdx.x;
    int wave = t >> 6, l = t & 63;
    int r0 = blockIdx.x * 64 + wave * 16;
    int lm = l & 15, q = l >> 4;

    int arow = r0 + lm;
    if (arow >= NN) arow = NN - 1;
    const unsigned short* xrow = X + (size_t)arow * DF + q * 8;
    short8 af0 = *(const short8*)(xrow);
    short8 af1 = *(const short8*)(xrow + 32);
    short8 af2 = *(const short8*)(xrow + 64);
    short8 af3 = *(const short8*)(xrow + 96);

    int orow = r0 + q * 4;
    float dv[4];
#pragma unroll
    for (int j = 0; j < 4; j++) dv[j] = (orow + j < NN) ? dinv[orow + j] : 0.f;

#pragma unroll
    for (int tt = 0; tt < 8; tt++) {
        floatx4 acc = {0.f, 0.f, 0.f, 0.f};
        const unsigned short* wp = Wb + ((size_t)(tt * 4) * 64 + l) * 8;
        acc = __builtin_amdgcn_mfma_f32_16x16x32_bf16(af0, *(const short8*)(wp), acc, 0, 0, 0);
        acc = __builtin_amdgcn_mfma_f32_16x16x32_bf16(af1, *(const short8*)(wp + 512), acc, 0, 0, 0);
        acc = __builtin_amdgcn_mfma_f32_16x16x32_bf16(af2, *(const short8*)(wp + 1024), acc, 0, 0, 0);
        acc = __builtin_amdgcn_mfma_f32_16x16x32_bf16(af3, *(const short8*)(wp + 1536), acc, 0, 0, 0);
        int c = tt * 16 + lm;
#pragma unroll
        for (int j = 0; j < 4; j++) {
            int r = orow + j;
            if (r < NN) hs[(size_t)r * DF + c] = f2bf(acc[j] * dv[j]);
        }
    }
}

__global__ __launch_bounds__(256) void k_agg(const unsigned short* __restrict__ hs,
                                             const int* __restrict__ rowptr,
                                             const int* __restrict__ col,
                                             const float* __restrict__ dinv,
                                             const float* __restrict__ b,
                                             unsigned short* __restrict__ out) {
    int n = (int)((blockIdx.x * (size_t)blockDim.x + threadIdx.x) >> 6);
    int lane = threadIdx.x & 63;
    if (n >= NN) return;
    int f = lane * 2;
    unsigned int sv = *(const unsigned int*)&hs[(size_t)n * DF + f];
    float ax = bf2f_lo(sv), ay = bf2f_hi(sv);
    int e = rowptr[n];
    int e1 = rowptr[n + 1];
    for (; e + 4 <= e1; e += 4) {
        int s0 = col[e], s1 = col[e + 1], s2 = col[e + 2], s3 = col[e + 3];
        unsigned int v0 = *(const unsigned int*)&hs[(size_t)s0 * DF + f];
        unsigned int v1 = *(const unsigned int*)&hs[(size_t)s1 * DF + f];
        unsigned int v2 = *(const unsigned int*)&hs[(size_t)s2 * DF + f];
        unsigned int v3 = *(const unsigned int*)&hs[(size_t)s3 * DF + f];
        ax += (bf2f_lo(v0) + bf2f_lo(v1)) + (bf2f_lo(v2) + bf2f_lo(v3));
        ay += (bf2f_hi(v0) + bf2f_hi(v1)) + (bf2f_hi(v2) + bf2f_hi(v3));
    }
    for (; e < e1; e++) {
        unsigned int v = *(const unsigned int*)&hs[(size_t)col[e] * DF + f];
        ax += bf2f_lo(v);
        ay += bf2f_hi(v);
    }
    float dvn = dinv[n];
    float2 bb = *(const float2*)&b[f];
    float ox = fmaxf(dvn * ax + bb.x, 0.f);
    float oy = fmaxf(dvn * ay + bb.y, 0.f);
    unsigned int packed = (unsigned int)f2bf(ox) | ((unsigned int)f2bf(oy) << 16);
    *(unsigned int*)&out[(size_t)n * DF + f] = packed;
}

// ---------------- pooling + FC ----------------

__global__ void k_bounds(const int* __restrict__ batch, int* __restrict__ gstart) {
    int g = threadIdx.x;
    if (g > NG) return;
    int lo = 0, hi = NN;
    while (lo < hi) {
        int mid = (lo + hi) >> 1;
        if (batch[mid] < g) lo = mid + 1; else hi = mid;
    }
    gstart[g] = lo;
}

// phase A: 8 chunks per graph, partial feature sums
__global__ __launch_bounds__(256) void k_poolA(const unsigned short* __restrict__ h,
                                               const int* __restrict__ gstart,
                                               float* __restrict__ part) {
    __shared__ float2 red[256];
    int g = blockIdx.x >> 3, c = blockIdx.x & 7;
    int s = gstart[g], e = gstart[g + 1];
    int len = e - s;
    int cs = s + (int)(((long long)len * c) >> 3);
    int ce = s + (int)(((long long)len * (c + 1)) >> 3);
    int t = threadIdx.x;
    int fp = t & 63;   // feature pair
    int rs = t >> 6;   // row-stride phase 0..3
    float2 acc = make_float2(0.f, 0.f);
    for (int n = cs + rs; n < ce; n += 4) {
        unsigned int v = *(const unsigned int*)&h[(size_t)n * DF + fp * 2];
        acc.x += bf2f_lo(v);
        acc.y += bf2f_hi(v);
    }
    red[t] = acc;
    __syncthreads();
    if (rs == 0) {
        float2 a0 = red[fp], a1 = red[fp + 64], a2 = red[fp + 128], a3 = red[fp + 192];
        float2 o;
        o.x = (a0.x + a1.x) + (a2.x + a3.x);
        o.y = (a0.y + a1.y) + (a2.y + a3.y);
        *(float2*)&part[(size_t)blockIdx.x * DF + fp * 2] = o;
    }
}

// phase B: reduce 8 partials, divide by count
__global__ __launch_bounds__(128) void k_poolB(const float* __restrict__ part,
                                               const int* __restrict__ gstart,
                                               float* __restrict__ pooled) {
    int g = blockIdx.x;
    int f = threadIdx.x;
    float s = 0.f;
#pragma unroll
    for (int c = 0; c < PCH; c++) s += part[(size_t)(g * PCH + c) * DF + f];
    int cnt = gstart[g + 1] - gstart[g];
    pooled[g * DF + f] = s / (float)max(cnt, 1);
}

__global__ __launch_bounds__(64) void k_fc(const float* __restrict__ pooled,
                                           const float* __restrict__ Wfc,
                                           const float* __restrict__ bfc,
                                           float* __restrict__ out) {
    int g = blockIdx.x;
    int o = threadIdx.x;
    float acc = bfc[o];
    for (int k = 0; k < DF; k++) acc += pooled[g * DF + k] * Wfc[k * DOUT + o];
    out[g * DOUT + o] = acc;
}

// ---------------- launch ----------------

extern "C" void kernel_launch(void* const* d_in, const int* in_sizes, int n_in,
                              void* d_out, int out_size, void* d_ws, size_t ws_size,
                              hipStream_t stream) {
    const float* x     = (const float*)d_in[0];
    const int*   ei    = (const int*)d_in[1];
    const int*   batch = (const int*)d_in[2];
    const float* W1 = (const float*)d_in[3];
    const float* b1 = (const float*)d_in[4];
    const float* W2 = (const float*)d_in[5];
    const float* b2 = (const float*)d_in[6];
    const float* W3 = (const float*)d_in[7];
    const float* b3 = (const float*)d_in[8];
    const float* Wfc = (const float*)d_in[9];
    const float* bfc = (const float*)d_in[10];
    float* out = (float*)d_out;

    char* p = (char*)d_ws;
    unsigned short* xb = (unsigned short*)p;  p += (size_t)NN * DF * sizeof(short);
    unsigned short* hs = (unsigned short*)p;  p += (size_t)NN * DF * sizeof(short);
    unsigned short* ob = (unsigned short*)p;  p += (size_t)NN * DF * sizeof(short);
    unsigned short* Wb1 = (unsigned short*)p; p += 16384 * sizeof(short);
    unsigned short* Wb2 = (unsigned short*)p; p += 16384 * sizeof(short);
    unsigned short* Wb3 = (unsigned short*)p; p += 16384 * sizeof(short);
    float* dinv = (float*)p;           p += (size_t)NN * sizeof(float);
    int* rowptr = (int*)p;             p += (size_t)(NN + 4) * sizeof(int);
    int* col    = (int*)p;             p += (size_t)NE * sizeof(int);
    int2* ebuf  = (int2*)p;            p += (size_t)NE * sizeof(int2);
    int* bhist  = (int*)p;             p += (size_t)(NB + 4) * sizeof(int);
    int* bbase  = (int*)p;             p += (size_t)(NB + 4) * sizeof(int);
    int* bcur   = (int*)p;             p += (size_t)(NB + 4) * sizeof(int);
    int* gstart = (int*)p;             p += (size_t)(NG + 4) * sizeof(int);
    float* pooled = (float*)p;         p += (size_t)NG * DF * sizeof(float);
    float* part  = (float*)p;          p += (size_t)NG * PCH * DF * sizeof(float);

    const int* e_src = ei;
    const int* e_dst = ei + NE;

    // CSR build
    k_zerob<<<(NB + 255) / 256, 256, 0, stream>>>(bhist);
    k_bcount<<<NBLKA, 256, 0, stream>>>(e_dst, bhist);
    k_bscan<<<1, 512, 0, stream>>>(bhist, bbase, bcur);
    k_pairs<<<NBLKA, 256, 0, stream>>>(e_src, e_dst, bcur, ebuf);
    k_build<<<NB, 256, 0, stream>>>(ebuf, bbase, rowptr, dinv, col);

    // bf16 conversions
    k_prepw<<<8, 256, 0, stream>>>(W1, Wb1);
    k_prepw<<<8, 256, 0, stream>>>(W2, Wb2);
    k_prepw<<<8, 256, 0, stream>>>(W3, Wb3);
    k_prepx<<<(NN * DF / 8 + 255) / 256, 256, 0, stream>>>(x, xb);

    int ggrid = (NN + 63) / 64;
    int agg_blocks = (NN + 3) / 4;

    // layer 1
    k_gemm<<<ggrid, 256, 0, stream>>>(xb, Wb1, dinv, hs);
    k_agg<<<agg_blocks, 256, 0, stream>>>(hs, rowptr, col, dinv, b1, ob);
    // layer 2
    k_gemm<<<ggrid, 256, 0, stream>>>(ob, Wb2, dinv, hs);
    k_agg<<<agg_blocks, 256, 0, stream>>>(hs, rowptr, col, dinv, b2, ob);
    // layer 3
    k_gemm<<<ggrid, 256, 0, stream>>>(ob, Wb3, dinv, hs);
    k_agg<<<agg_blocks, 256, 0, stream>>>(hs, rowptr, col, dinv, b3, ob);

    // pool + fc
    k_bounds<<<1, 256, 0, stream>>>(batch, gstart);
    k_poolA<<<NG * PCH, 256, 0, stream>>>(ob, gstart, part);
    k_poolB<<<NG, 128, 0, stream>>>(part, gstart, pooled);
    k_fc<<<NG, 64, 0, stream>>>(pooled, Wfc, bfc, out);
}

// Round 7
// 449.372 us; speedup vs baseline: 1.8479x; 1.0377x over previous
//
#include <hip/hip_runtime.h>

#define NN 100000
#define NE 1600000
#define DF 128
#define DOUT 64
#define NG 128
#define NB 391      // ceil(NN/256) buckets of 256 nodes
#define EPB 8192    // edges per block in binning passes
#define NBLKA ((NE + EPB - 1) / EPB)  // 196
#define PCH 8       // pool chunks per graph

typedef short short8 __attribute__((ext_vector_type(8)));
typedef float floatx4 __attribute__((ext_vector_type(4)));

__device__ __forceinline__ unsigned short f2bf(float f) {
    unsigned int b = __float_as_uint(f);
    unsigned int r = (b + 0x7fffu + ((b >> 16) & 1u)) >> 16;
    return (unsigned short)r;
}
__device__ __forceinline__ float bf2f_lo(unsigned int v) { return __uint_as_float(v << 16); }
__device__ __forceinline__ float bf2f_hi(unsigned int v) { return __uint_as_float(v & 0xffff0000u); }

// physical feature index p -> logical feature c.
// p = g*64 + lm*4 + u  (g:0..1, lm:0..15, u:0..3), c = (g*4+u)*16 + lm
__device__ __forceinline__ int phi(int p) {
    return (((p >> 6) << 2) + (p & 3)) * 16 + ((p >> 2) & 15);
}

// ---------------- CSR build: LDS-binned radix partition ----------------

// blocks 0-1: zero bhist; block 2: graph bounds via binary search
__global__ void k_init(int* __restrict__ bhist, const int* __restrict__ batch,
                       int* __restrict__ gstart) {
    if (blockIdx.x < 2) {
        int i = blockIdx.x * 256 + threadIdx.x;
        if (i < NB) bhist[i] = 0;
    } else {
        int g = threadIdx.x;
        if (g > NG) return;
        int lo = 0, hi = NN;
        while (lo < hi) {
            int mid = (lo + hi) >> 1;
            if (batch[mid] < g) lo = mid + 1; else hi = mid;
        }
        gstart[g] = lo;
    }
}

__global__ __launch_bounds__(256) void k_bcount(const int* __restrict__ dst,
                                                int* __restrict__ bhist) {
    __shared__ int lh[NB];
    int t = threadIdx.x;
    for (int i = t; i < NB; i += 256) lh[i] = 0;
    __syncthreads();
    int e0 = blockIdx.x * EPB;
    int e1 = min(e0 + EPB, NE);
    for (int e = e0 + t; e < e1; e += 256) atomicAdd(&lh[dst[e] >> 8], 1);
    __syncthreads();
    for (int i = t; i < NB; i += 256) {
        int c = lh[i];
        if (c) atomicAdd(&bhist[i], c);
    }
}

__global__ __launch_bounds__(512) void k_bscan(const int* __restrict__ bhist,
                                               int* __restrict__ bbase,
                                               int* __restrict__ bcur) {
    __shared__ int sh[512];
    int t = threadIdx.x;
    int v = (t < NB) ? bhist[t] : 0;
    sh[t] = v;
    __syncthreads();
    for (int off = 1; off < 512; off <<= 1) {
        int a = (t >= off) ? sh[t - off] : 0;
        __syncthreads();
        sh[t] += a;
        __syncthreads();
    }
    if (t < NB) {
        bbase[t] = sh[t] - v;
        bcur[t] = sh[t] - v;
    }
    if (t == NB - 1) bbase[NB] = sh[t];
}

__global__ __launch_bounds__(256) void k_pairs(const int* __restrict__ src,
                                               const int* __restrict__ dst,
                                               int* __restrict__ bcur,
                                               int2* __restrict__ ebuf) {
    __shared__ int lh[NB];
    __shared__ int lbase[NB];
    int t = threadIdx.x;
    for (int i = t; i < NB; i += 256) lh[i] = 0;
    __syncthreads();
    int e0 = blockIdx.x * EPB;
    int e1 = min(e0 + EPB, NE);
    for (int e = e0 + t; e < e1; e += 256) atomicAdd(&lh[dst[e] >> 8], 1);
    __syncthreads();
    for (int i = t; i < NB; i += 256) {
        int c = lh[i];
        lbase[i] = c ? atomicAdd(&bcur[i], c) : 0;
    }
    __syncthreads();
    for (int i = t; i < NB; i += 256) lh[i] = 0;
    __syncthreads();
    for (int e = e0 + t; e < e1; e += 256) {
        int s = src[e], d = dst[e];
        int bk = d >> 8;
        int off = atomicAdd(&lh[bk], 1);
        ebuf[lbase[bk] + off] = make_int2(s, d);
    }
}

__global__ __launch_bounds__(256) void k_build(const int2* __restrict__ ebuf,
                                               const int* __restrict__ bbase,
                                               int* __restrict__ rowptr,
                                               float* __restrict__ dinv,
                                               int* __restrict__ col) {
    __shared__ int deg[256];
    __shared__ int lst[256];
    int b = blockIdx.x, t = threadIdx.x;
    int n0 = b << 8;
    int node = n0 + t;
    deg[t] = 0;
    __syncthreads();
    int e0 = bbase[b], e1 = bbase[b + 1];
    for (int e = e0 + t; e < e1; e += 256) atomicAdd(&deg[ebuf[e].y - n0], 1);
    __syncthreads();
    int v = deg[t];
    lst[t] = v;
    __syncthreads();
    for (int off = 1; off < 256; off <<= 1) {
        int a = (t >= off) ? lst[t - off] : 0;
        __syncthreads();
        lst[t] += a;
        __syncthreads();
    }
    int mystart = e0 + lst[t] - v;
    if (node < NN) {
        rowptr[node] = mystart;
        dinv[node] = rsqrtf((float)(v + 1));  // +1 self-loop
    }
    if (b == NB - 1 && t == 255) rowptr[NN] = e1;
    lst[t] = mystart;
    __syncthreads();
    for (int e = e0 + t; e < e1; e += 256) {
        int2 pr = ebuf[e];
        int p = atomicAdd(&lst[pr.y - n0], 1);
        col[p] = pr.x;
    }
}

// ---------------- bf16 conversions ----------------

// all 3 weights in one launch; fragment k-rows follow physical X layout via phi
__global__ __launch_bounds__(256) void k_prepw(const float* __restrict__ Wa,
                                               const float* __restrict__ Wbm,
                                               const float* __restrict__ Wc,
                                               unsigned short* __restrict__ Oa,
                                               unsigned short* __restrict__ Ob,
                                               unsigned short* __restrict__ Oc) {
    const float* W = (blockIdx.y == 0) ? Wa : (blockIdx.y == 1) ? Wbm : Wc;
    unsigned short* O = (blockIdx.y == 0) ? Oa : (blockIdx.y == 1) ? Ob : Oc;
    int idx = blockIdx.x * 256 + threadIdx.x;
    if (idx >= 2048) return;
    int l = idx & 63;
    int s = (idx >> 6) & 3;
    int t = idx >> 8;
    int k0 = s * 32 + (l >> 4) * 8;
    int c = t * 16 + (l & 15);
    unsigned short o[8];
#pragma unroll
    for (int j = 0; j < 8; j++) o[j] = f2bf(W[phi(k0 + j) * DF + c]);
    *(short8*)&O[idx * 8] = *(short8*)o;
}

// x f32 -> bf16, permuted feature order
__global__ __launch_bounds__(256) void k_prepx(const float* __restrict__ x,
                                               unsigned short* __restrict__ xb) {
    size_t i = ((size_t)blockIdx.x * 256 + threadIdx.x) * 8;
    if (i >= (size_t)NN * DF) return;
    size_t rb = i & ~(size_t)127;  // row base
    int p0 = (int)(i & 127);
    unsigned short o[8];
#pragma unroll
    for (int j = 0; j < 8; j++) o[j] = f2bf(x[rb + phi(p0 + j)]);
    *(short8*)&xb[i] = *(short8*)o;
}

// ---------------- per-layer compute ----------------

// hs (bf16, physical layout) + fs8 (fp8 e4m3 copy for neighbor gathers)
__global__ __launch_bounds__(256) void k_gemm(const unsigned short* __restrict__ X,
                                              const unsigned short* __restrict__ Wb,
                                              const float* __restrict__ dinv,
                                              unsigned short* __restrict__ hs,
                                              unsigned char* __restrict__ fs8) {
    int t = threadIdx.x;
    int wave = t >> 6, l = t & 63;
    int r0 = blockIdx.x * 64 + wave * 16;
    int lm = l & 15, q = l >> 4;

    int arow = r0 + lm;
    if (arow >= NN) arow = NN - 1;
    const unsigned short* xrow = X + (size_t)arow * DF + q * 8;
    short8 af0 = *(const short8*)(xrow);
    short8 af1 = *(const short8*)(xrow + 32);
    short8 af2 = *(const short8*)(xrow + 64);
    short8 af3 = *(const short8*)(xrow + 96);

    int orow = r0 + q * 4;
    float dv[4];
#pragma unroll
    for (int j = 0; j < 4; j++) dv[j] = (orow + j < NN) ? dinv[orow + j] : 0.f;

    float res[4][8];
#pragma unroll
    for (int tt = 0; tt < 8; tt++) {
        floatx4 acc = {0.f, 0.f, 0.f, 0.f};
        const unsigned short* wp = Wb + ((size_t)(tt * 4) * 64 + l) * 8;
        acc = __builtin_amdgcn_mfma_f32_16x16x32_bf16(af0, *(const short8*)(wp), acc, 0, 0, 0);
        acc = __builtin_amdgcn_mfma_f32_16x16x32_bf16(af1, *(const short8*)(wp + 512), acc, 0, 0, 0);
        acc = __builtin_amdgcn_mfma_f32_16x16x32_bf16(af2, *(const short8*)(wp + 1024), acc, 0, 0, 0);
        acc = __builtin_amdgcn_mfma_f32_16x16x32_bf16(af3, *(const short8*)(wp + 1536), acc, 0, 0, 0);
#pragma unroll
        for (int j = 0; j < 4; j++) res[j][tt] = acc[j] * dv[j];
    }

    // epilogue: physical layout p = g*64 + lm*4 + u holds logical col (g*4+u)*16+lm
#pragma unroll
    for (int g = 0; g < 2; g++) {
#pragma unroll
        for (int j = 0; j < 4; j++) {
            int r = orow + j;
            if (r >= NN) continue;
            float v0 = res[j][g * 4 + 0], v1 = res[j][g * 4 + 1];
            float v2 = res[j][g * 4 + 2], v3 = res[j][g * 4 + 3];
            uint2 bfp;
            bfp.x = (unsigned int)f2bf(v0) | ((unsigned int)f2bf(v1) << 16);
            bfp.y = (unsigned int)f2bf(v2) | ((unsigned int)f2bf(v3) << 16);
            int p = g * 64 + lm * 4;
            *(uint2*)&hs[(size_t)r * DF + p] = bfp;
            unsigned int w8 = __builtin_amdgcn_cvt_pk_fp8_f32(v0, v1, 0, false);
            w8 = __builtin_amdgcn_cvt_pk_fp8_f32(v2, v3, w8, true);
            *(unsigned int*)&fs8[(size_t)r * DF + p] = w8;
        }
    }
}

// out[n] = bf16(relu(dinv*(hs_self + sum fp8 neighbor rows) + b)), physical layout
__global__ __launch_bounds__(256) void k_agg(const unsigned short* __restrict__ hs,
                                             const unsigned char* __restrict__ fs8,
                                             const int* __restrict__ rowptr,
                                             const int* __restrict__ col,
                                             const float* __restrict__ dinv,
                                             const float* __restrict__ b,
                                             unsigned short* __restrict__ out) {
    int n = (int)((blockIdx.x * (size_t)blockDim.x + threadIdx.x) >> 6);
    int lane = threadIdx.x & 63;
    if (n >= NN) return;
    int f = lane * 2;
    unsigned int sv = *(const unsigned int*)&hs[(size_t)n * DF + f];
    float ax = bf2f_lo(sv), ay = bf2f_hi(sv);
    int e = rowptr[n];
    int e1 = rowptr[n + 1];
    for (; e + 4 <= e1; e += 4) {
        int s0 = col[e], s1 = col[e + 1], s2 = col[e + 2], s3 = col[e + 3];
        int v0 = *(const unsigned short*)&fs8[(size_t)s0 * DF + f];
        int v1 = *(const unsigned short*)&fs8[(size_t)s1 * DF + f];
        int v2 = *(const unsigned short*)&fs8[(size_t)s2 * DF + f];
        int v3 = *(const unsigned short*)&fs8[(size_t)s3 * DF + f];
        ax += (__builtin_amdgcn_cvt_f32_fp8(v0, 0) + __builtin_amdgcn_cvt_f32_fp8(v1, 0)) +
              (__builtin_amdgcn_cvt_f32_fp8(v2, 0) + __builtin_amdgcn_cvt_f32_fp8(v3, 0));
        ay += (__builtin_amdgcn_cvt_f32_fp8(v0, 1) + __builtin_amdgcn_cvt_f32_fp8(v1, 1)) +
              (__builtin_amdgcn_cvt_f32_fp8(v2, 1) + __builtin_amdgcn_cvt_f32_fp8(v3, 1));
    }
    for (; e < e1; e++) {
        int v = *(const unsigned short*)&fs8[(size_t)col[e] * DF + f];
        ax += __builtin_amdgcn_cvt_f32_fp8(v, 0);
        ay += __builtin_amdgcn_cvt_f32_fp8(v, 1);
    }
    float dvn = dinv[n];
    float bx = b[phi(f)], by = b[phi(f + 1)];
    float ox = fmaxf(dvn * ax + bx, 0.f);
    float oy = fmaxf(dvn * ay + by, 0.f);
    unsigned int packed = (unsigned int)f2bf(ox) | ((unsigned int)f2bf(oy) << 16);
    *(unsigned int*)&out[(size_t)n * DF + f] = packed;
}

// ---------------- pooling + FC ----------------

__global__ __launch_bounds__(256) void k_poolA(const unsigned short* __restrict__ h,
                                               const int* __restrict__ gstart,
                                               float* __restrict__ part) {
    __shared__ float2 red[256];
    int g = blockIdx.x >> 3, c = blockIdx.x & 7;
    int s = gstart[g], e = gstart[g + 1];
    int len = e - s;
    int cs = s + (int)(((long long)len * c) >> 3);
    int ce = s + (int)(((long long)len * (c + 1)) >> 3);
    int t = threadIdx.x;
    int fp = t & 63;
    int rs = t >> 6;
    float2 acc = make_float2(0.f, 0.f);
    for (int n = cs + rs; n < ce; n += 4) {
        unsigned int v = *(const unsigned int*)&h[(size_t)n * DF + fp * 2];
        acc.x += bf2f_lo(v);
        acc.y += bf2f_hi(v);
    }
    red[t] = acc;
    __syncthreads();
    if (rs == 0) {
        float2 a0 = red[fp], a1 = red[fp + 64], a2 = red[fp + 128], a3 = red[fp + 192];
        float2 o;
        o.x = (a0.x + a1.x) + (a2.x + a3.x);
        o.y = (a0.y + a1.y) + (a2.y + a3.y);
        *(float2*)&part[(size_t)blockIdx.x * DF + fp * 2] = o;
    }
}

// reduce partials, divide by count, un-permute to logical order
__global__ __launch_bounds__(128) void k_poolB(const float* __restrict__ part,
                                               const int* __restrict__ gstart,
                                               float* __restrict__ pooled) {
    int g = blockIdx.x;
    int f = threadIdx.x;
    float s = 0.f;
#pragma unroll
    for (int c = 0; c < PCH; c++) s += part[(size_t)(g * PCH + c) * DF + f];
    int cnt = gstart[g + 1] - gstart[g];
    pooled[g * DF + phi(f)] = s / (float)max(cnt, 1);
}

__global__ __launch_bounds__(64) void k_fc(const float* __restrict__ pooled,
                                           const float* __restrict__ Wfc,
                                           const float* __restrict__ bfc,
                                           float* __restrict__ out) {
    int g = blockIdx.x;
    int o = threadIdx.x;
    float acc = bfc[o];
    for (int k = 0; k < DF; k++) acc += pooled[g * DF + k] * Wfc[k * DOUT + o];
    out[g * DOUT + o] = acc;
}

// ---------------- launch ----------------

extern "C" void kernel_launch(void* const* d_in, const int* in_sizes, int n_in,
                              void* d_out, int out_size, void* d_ws, size_t ws_size,
                              hipStream_t stream) {
    const float* x     = (const float*)d_in[0];
    const int*   ei    = (const int*)d_in[1];
    const int*   batch = (const int*)d_in[2];
    const float* W1 = (const float*)d_in[3];
    const float* b1 = (const float*)d_in[4];
    const float* W2 = (const float*)d_in[5];
    const float* b2 = (const float*)d_in[6];
    const float* W3 = (const float*)d_in[7];
    const float* b3 = (const float*)d_in[8];
    const float* Wfc = (const float*)d_in[9];
    const float* bfc = (const float*)d_in[10];
    float* out = (float*)d_out;

    char* p = (char*)d_ws;
    unsigned short* xb = (unsigned short*)p;  p += (size_t)NN * DF * sizeof(short);
    unsigned short* hs = (unsigned short*)p;  p += (size_t)NN * DF * sizeof(short);
    unsigned short* ob = (unsigned short*)p;  p += (size_t)NN * DF * sizeof(short);
    unsigned char*  fs8 = (unsigned char*)p;  p += (size_t)NN * DF;
    unsigned short* Wb1 = (unsigned short*)p; p += 16384 * sizeof(short);
    unsigned short* Wb2 = (unsigned short*)p; p += 16384 * sizeof(short);
    unsigned short* Wb3 = (unsigned short*)p; p += 16384 * sizeof(short);
    float* dinv = (float*)p;           p += (size_t)NN * sizeof(float);
    int* rowptr = (int*)p;             p += (size_t)(NN + 4) * sizeof(int);
    int* col    = (int*)p;             p += (size_t)NE * sizeof(int);
    int2* ebuf  = (int2*)p;            p += (size_t)NE * sizeof(int2);
    int* bhist  = (int*)p;             p += (size_t)(NB + 4) * sizeof(int);
    int* bbase  = (int*)p;             p += (size_t)(NB + 4) * sizeof(int);
    int* bcur   = (int*)p;             p += (size_t)(NB + 4) * sizeof(int);
    int* gstart = (int*)p;             p += (size_t)(NG + 4) * sizeof(int);
    float* pooled = (float*)p;         p += (size_t)NG * DF * sizeof(float);
    float* part  = (float*)p;          p += (size_t)NG * PCH * DF * sizeof(float);

    const int* e_src = ei;
    const int* e_dst = ei + NE;

    // CSR build + graph bounds
    k_init<<<3, 256, 0, stream>>>(bhist, batch, gstart);
    k_bcount<<<NBLKA, 256, 0, stream>>>(e_dst, bhist);
    k_bscan<<<1, 512, 0, stream>>>(bhist, bbase, bcur);
    k_pairs<<<NBLKA, 256, 0, stream>>>(e_src, e_dst, bcur, ebuf);
    k_build<<<NB, 256, 0, stream>>>(ebuf, bbase, rowptr, dinv, col);

    // bf16 conversions
    k_prepw<<<dim3(8, 3), 256, 0, stream>>>(W1, W2, W3, Wb1, Wb2, Wb3);
    k_prepx<<<(NN * DF / 8 + 255) / 256, 256, 0, stream>>>(x, xb);

    int ggrid = (NN + 63) / 64;
    int agg_blocks = (NN + 3) / 4;

    // layer 1
    k_gemm<<<ggrid, 256, 0, stream>>>(xb, Wb1, dinv, hs, fs8);
    k_agg<<<agg_blocks, 256, 0, stream>>>(hs, fs8, rowptr, col, dinv, b1, ob);
    // layer 2
    k_gemm<<<ggrid, 256, 0, stream>>>(ob, Wb2, dinv, hs, fs8);
    k_agg<<<agg_blocks, 256, 0, stream>>>(hs, fs8, rowptr, col, dinv, b2, ob);
    // layer 3
    k_gemm<<<ggrid, 256, 0, stream>>>(ob, Wb3, dinv, hs, fs8);
    k_agg<<<agg_blocks, 256, 0, stream>>>(hs, fs8, rowptr, col, dinv, b3, ob);

    // pool + fc
    k_poolA<<<NG * PCH, 256, 0, stream>>>(ob, gstart, part);
    k_poolB<<<NG, 128, 0, stream>>>(part, gstart, pooled);
    k_fc<<<NG, 64, 0, stream>>>(pooled, Wfc, bfc, out);
}

// Round 8
// 442.961 us; speedup vs baseline: 1.8747x; 1.0145x over previous
//
#include <hip/hip_runtime.h>

#define NN 100000
#define NE 1600000
#define DF 128
#define DOUT 64
#define NG 128
#define NB 391      // ceil(NN/256) buckets of 256 nodes
#define EPB 8192    // edges per block in binning passes
#define NBLKA ((NE + EPB - 1) / EPB)  // 196
#define PCH 8       // pool chunks per graph

typedef short short8 __attribute__((ext_vector_type(8)));
typedef float floatx4 __attribute__((ext_vector_type(4)));

__device__ __forceinline__ unsigned short f2bf(float f) {
    unsigned int b = __float_as_uint(f);
    unsigned int r = (b + 0x7fffu + ((b >> 16) & 1u)) >> 16;
    return (unsigned short)r;
}
__device__ __forceinline__ float bf2f_lo(unsigned int v) { return __uint_as_float(v << 16); }
__device__ __forceinline__ float bf2f_hi(unsigned int v) { return __uint_as_float(v & 0xffff0000u); }

// physical feature index p -> logical feature c.
// p = g*64 + lm*4 + u  (g:0..1, lm:0..15, u:0..3), c = (g*4+u)*16 + lm
__device__ __forceinline__ int phi(int p) {
    return (((p >> 6) << 2) + (p & 3)) * 16 + ((p >> 2) & 15);
}

// ---------------- CSR build: LDS-binned radix partition ----------------

__global__ void k_init(int* __restrict__ bhist, const int* __restrict__ batch,
                       int* __restrict__ gstart) {
    if (blockIdx.x < 2) {
        int i = blockIdx.x * 256 + threadIdx.x;
        if (i < NB) bhist[i] = 0;
    } else {
        int g = threadIdx.x;
        if (g > NG) return;
        int lo = 0, hi = NN;
        while (lo < hi) {
            int mid = (lo + hi) >> 1;
            if (batch[mid] < g) lo = mid + 1; else hi = mid;
        }
        gstart[g] = lo;
    }
}

__global__ __launch_bounds__(256) void k_bcount(const int* __restrict__ dst,
                                                int* __restrict__ bhist) {
    __shared__ int lh[NB];
    int t = threadIdx.x;
    for (int i = t; i < NB; i += 256) lh[i] = 0;
    __syncthreads();
    int e0 = blockIdx.x * EPB;
    int e1 = min(e0 + EPB, NE);
    for (int e = e0 + t; e < e1; e += 256) atomicAdd(&lh[dst[e] >> 8], 1);
    __syncthreads();
    for (int i = t; i < NB; i += 256) {
        int c = lh[i];
        if (c) atomicAdd(&bhist[i], c);
    }
}

__global__ __launch_bounds__(512) void k_bscan(const int* __restrict__ bhist,
                                               int* __restrict__ bbase,
                                               int* __restrict__ bcur) {
    __shared__ int sh[512];
    int t = threadIdx.x;
    int v = (t < NB) ? bhist[t] : 0;
    sh[t] = v;
    __syncthreads();
    for (int off = 1; off < 512; off <<= 1) {
        int a = (t >= off) ? sh[t - off] : 0;
        __syncthreads();
        sh[t] += a;
        __syncthreads();
    }
    if (t < NB) {
        bbase[t] = sh[t] - v;
        bcur[t] = sh[t] - v;
    }
    if (t == NB - 1) bbase[NB] = sh[t];
}

__global__ __launch_bounds__(256) void k_pairs(const int* __restrict__ src,
                                               const int* __restrict__ dst,
                                               int* __restrict__ bcur,
                                               int2* __restrict__ ebuf) {
    __shared__ int lh[NB];
    __shared__ int lbase[NB];
    int t = threadIdx.x;
    for (int i = t; i < NB; i += 256) lh[i] = 0;
    __syncthreads();
    int e0 = blockIdx.x * EPB;
    int e1 = min(e0 + EPB, NE);
    for (int e = e0 + t; e < e1; e += 256) atomicAdd(&lh[dst[e] >> 8], 1);
    __syncthreads();
    for (int i = t; i < NB; i += 256) {
        int c = lh[i];
        lbase[i] = c ? atomicAdd(&bcur[i], c) : 0;
    }
    __syncthreads();
    for (int i = t; i < NB; i += 256) lh[i] = 0;
    __syncthreads();
    for (int e = e0 + t; e < e1; e += 256) {
        int s = src[e], d = dst[e];
        int bk = d >> 8;
        int off = atomicAdd(&lh[bk], 1);
        ebuf[lbase[bk] + off] = make_int2(s, d);
    }
}

__global__ __launch_bounds__(256) void k_build(const int2* __restrict__ ebuf,
                                               const int* __restrict__ bbase,
                                               int* __restrict__ rowptr,
                                               float* __restrict__ dinv,
                                               int* __restrict__ col) {
    __shared__ int deg[256];
    __shared__ int lst[256];
    int b = blockIdx.x, t = threadIdx.x;
    int n0 = b << 8;
    int node = n0 + t;
    deg[t] = 0;
    __syncthreads();
    int e0 = bbase[b], e1 = bbase[b + 1];
    for (int e = e0 + t; e < e1; e += 256) atomicAdd(&deg[ebuf[e].y - n0], 1);
    __syncthreads();
    int v = deg[t];
    lst[t] = v;
    __syncthreads();
    for (int off = 1; off < 256; off <<= 1) {
        int a = (t >= off) ? lst[t - off] : 0;
        __syncthreads();
        lst[t] += a;
        __syncthreads();
    }
    int mystart = e0 + lst[t] - v;
    if (node < NN) {
        rowptr[node] = mystart;
        dinv[node] = rsqrtf((float)(v + 1));  // +1 self-loop
    }
    if (b == NB - 1 && t == 255) rowptr[NN] = e1;
    lst[t] = mystart;
    __syncthreads();
    for (int e = e0 + t; e < e1; e += 256) {
        int2 pr = ebuf[e];
        int p = atomicAdd(&lst[pr.y - n0], 1);
        col[p] = pr.x;
    }
}

// ---------------- bf16 conversions ----------------

__global__ __launch_bounds__(256) void k_prepw(const float* __restrict__ Wa,
                                               const float* __restrict__ Wbm,
                                               const float* __restrict__ Wc,
                                               unsigned short* __restrict__ Oa,
                                               unsigned short* __restrict__ Ob,
                                               unsigned short* __restrict__ Oc) {
    const float* W = (blockIdx.y == 0) ? Wa : (blockIdx.y == 1) ? Wbm : Wc;
    unsigned short* O = (blockIdx.y == 0) ? Oa : (blockIdx.y == 1) ? Ob : Oc;
    int idx = blockIdx.x * 256 + threadIdx.x;
    if (idx >= 2048) return;
    int l = idx & 63;
    int s = (idx >> 6) & 3;
    int t = idx >> 8;
    int k0 = s * 32 + (l >> 4) * 8;
    int c = t * 16 + (l & 15);
    unsigned short o[8];
#pragma unroll
    for (int j = 0; j < 8; j++) o[j] = f2bf(W[phi(k0 + j) * DF + c]);
    *(short8*)&O[idx * 8] = *(short8*)o;
}

__global__ __launch_bounds__(256) void k_prepx(const float* __restrict__ x,
                                               unsigned short* __restrict__ xb) {
    size_t i = ((size_t)blockIdx.x * 256 + threadIdx.x) * 8;
    if (i >= (size_t)NN * DF) return;
    size_t rb = i & ~(size_t)127;
    int p0 = (int)(i & 127);
    unsigned short o[8];
#pragma unroll
    for (int j = 0; j < 8; j++) o[j] = f2bf(x[rb + phi(p0 + j)]);
    *(short8*)&xb[i] = *(short8*)o;
}

// ---------------- per-layer compute ----------------

__global__ __launch_bounds__(256) void k_gemm(const unsigned short* __restrict__ X,
                                              const unsigned short* __restrict__ Wb,
                                              const float* __restrict__ dinv,
                                              unsigned short* __restrict__ hs,
                                              unsigned char* __restrict__ fs8) {
    int t = threadIdx.x;
    int wave = t >> 6, l = t & 63;
    int r0 = blockIdx.x * 64 + wave * 16;
    int lm = l & 15, q = l >> 4;

    int arow = r0 + lm;
    if (arow >= NN) arow = NN - 1;
    const unsigned short* xrow = X + (size_t)arow * DF + q * 8;
    short8 af0 = *(const short8*)(xrow);
    short8 af1 = *(const short8*)(xrow + 32);
    short8 af2 = *(const short8*)(xrow + 64);
    short8 af3 = *(const short8*)(xrow + 96);

    int orow = r0 + q * 4;
    float dv[4];
#pragma unroll
    for (int j = 0; j < 4; j++) dv[j] = (orow + j < NN) ? dinv[orow + j] : 0.f;

    float res[4][8];
#pragma unroll
    for (int tt = 0; tt < 8; tt++) {
        floatx4 acc = {0.f, 0.f, 0.f, 0.f};
        const unsigned short* wp = Wb + ((size_t)(tt * 4) * 64 + l) * 8;
        acc = __builtin_amdgcn_mfma_f32_16x16x32_bf16(af0, *(const short8*)(wp), acc, 0, 0, 0);
        acc = __builtin_amdgcn_mfma_f32_16x16x32_bf16(af1, *(const short8*)(wp + 512), acc, 0, 0, 0);
        acc = __builtin_amdgcn_mfma_f32_16x16x32_bf16(af2, *(const short8*)(wp + 1024), acc, 0, 0, 0);
        acc = __builtin_amdgcn_mfma_f32_16x16x32_bf16(af3, *(const short8*)(wp + 1536), acc, 0, 0, 0);
#pragma unroll
        for (int j = 0; j < 4; j++) res[j][tt] = acc[j] * dv[j];
    }

#pragma unroll
    for (int g = 0; g < 2; g++) {
#pragma unroll
        for (int j = 0; j < 4; j++) {
            int r = orow + j;
            if (r >= NN) continue;
            float v0 = res[j][g * 4 + 0], v1 = res[j][g * 4 + 1];
            float v2 = res[j][g * 4 + 2], v3 = res[j][g * 4 + 3];
            uint2 bfp;
            bfp.x = (unsigned int)f2bf(v0) | ((unsigned int)f2bf(v1) << 16);
            bfp.y = (unsigned int)f2bf(v2) | ((unsigned int)f2bf(v3) << 16);
            int p = g * 64 + lm * 4;
            *(uint2*)&hs[(size_t)r * DF + p] = bfp;
            unsigned int w8 = __builtin_amdgcn_cvt_pk_fp8_f32(v0, v1, 0, false);
            w8 = __builtin_amdgcn_cvt_pk_fp8_f32(v2, v3, w8, true);
            *(unsigned int*)&fs8[(size_t)r * DF + p] = w8;
        }
    }
}

// 1 wave per node; lane = (sub 0..3, fo 0..15); each iteration gathers 4 edges'
// fp8 rows in ONE load instruction (uint2/lane, 512B/wave). Cross-sub reduce
// via shfl_xor; 16-lane uint4 epilogue store.
__global__ __launch_bounds__(256) void k_agg(const unsigned short* __restrict__ hs,
                                             const unsigned char* __restrict__ fs8,
                                             const int* __restrict__ rowptr,
                                             const int* __restrict__ col,
                                             const float* __restrict__ dinv,
                                             const float* __restrict__ b,
                                             unsigned short* __restrict__ out) {
    int n = (int)((blockIdx.x * (size_t)blockDim.x + threadIdx.x) >> 6);
    int lane = threadIdx.x & 63;
    int sub = lane >> 4;       // which edge of the group of 4
    int fo = lane & 15;        // feature octet: physical features fo*8..fo*8+7
    int foff = fo * 8;

    int e0 = rowptr[n], e1 = rowptr[n + 1];

    float acc[8] = {0.f, 0.f, 0.f, 0.f, 0.f, 0.f, 0.f, 0.f};
    for (int e = e0; e < e1; e += 4) {
        int idx = e + sub;
        int cs = col[min(idx, e1 - 1)];
        uint2 v = *(const uint2*)&fs8[(size_t)cs * DF + foff];
        if (idx < e1) {
            acc[0] += __builtin_amdgcn_cvt_f32_fp8(v.x, 0);
            acc[1] += __builtin_amdgcn_cvt_f32_fp8(v.x, 1);
            acc[2] += __builtin_amdgcn_cvt_f32_fp8(v.x, 2);
            acc[3] += __builtin_amdgcn_cvt_f32_fp8(v.x, 3);
            acc[4] += __builtin_amdgcn_cvt_f32_fp8(v.y, 0);
            acc[5] += __builtin_amdgcn_cvt_f32_fp8(v.y, 1);
            acc[6] += __builtin_amdgcn_cvt_f32_fp8(v.y, 2);
            acc[7] += __builtin_amdgcn_cvt_f32_fp8(v.y, 3);
        }
    }
#pragma unroll
    for (int j = 0; j < 8; j++) {
        acc[j] += __shfl_xor(acc[j], 16);
        acc[j] += __shfl_xor(acc[j], 32);
    }

    if (sub == 0) {
        uint4 sv = *(const uint4*)&hs[(size_t)n * DF + foff];
        float dvn = dinv[n];
        float s0 = bf2f_lo(sv.x), s1 = bf2f_hi(sv.x);
        float s2 = bf2f_lo(sv.y), s3 = bf2f_hi(sv.y);
        float s4 = bf2f_lo(sv.z), s5 = bf2f_hi(sv.z);
        float s6 = bf2f_lo(sv.w), s7 = bf2f_hi(sv.w);
        float o[8];
        o[0] = fmaxf(dvn * (acc[0] + s0) + b[phi(foff + 0)], 0.f);
        o[1] = fmaxf(dvn * (acc[1] + s1) + b[phi(foff + 1)], 0.f);
        o[2] = fmaxf(dvn * (acc[2] + s2) + b[phi(foff + 2)], 0.f);
        o[3] = fmaxf(dvn * (acc[3] + s3) + b[phi(foff + 3)], 0.f);
        o[4] = fmaxf(dvn * (acc[4] + s4) + b[phi(foff + 4)], 0.f);
        o[5] = fmaxf(dvn * (acc[5] + s5) + b[phi(foff + 5)], 0.f);
        o[6] = fmaxf(dvn * (acc[6] + s6) + b[phi(foff + 6)], 0.f);
        o[7] = fmaxf(dvn * (acc[7] + s7) + b[phi(foff + 7)], 0.f);
        uint4 pk;
        pk.x = (unsigned int)f2bf(o[0]) | ((unsigned int)f2bf(o[1]) << 16);
        pk.y = (unsigned int)f2bf(o[2]) | ((unsigned int)f2bf(o[3]) << 16);
        pk.z = (unsigned int)f2bf(o[4]) | ((unsigned int)f2bf(o[5]) << 16);
        pk.w = (unsigned int)f2bf(o[6]) | ((unsigned int)f2bf(o[7]) << 16);
        *(uint4*)&out[(size_t)n * DF + foff] = pk;
    }
}

// ---------------- pooling + FC ----------------

__global__ __launch_bounds__(256) void k_poolA(const unsigned short* __restrict__ h,
                                               const int* __restrict__ gstart,
                                               float* __restrict__ part) {
    __shared__ float2 red[256];
    int g = blockIdx.x >> 3, c = blockIdx.x & 7;
    int s = gstart[g], e = gstart[g + 1];
    int len = e - s;
    int cs = s + (int)(((long long)len * c) >> 3);
    int ce = s + (int)(((long long)len * (c + 1)) >> 3);
    int t = threadIdx.x;
    int fp = t & 63;
    int rs = t >> 6;
    float2 acc = make_float2(0.f, 0.f);
    for (int n = cs + rs; n < ce; n += 4) {
        unsigned int v = *(const unsigned int*)&h[(size_t)n * DF + fp * 2];
        acc.x += bf2f_lo(v);
        acc.y += bf2f_hi(v);
    }
    red[t] = acc;
    __syncthreads();
    if (rs == 0) {
        float2 a0 = red[fp], a1 = red[fp + 64], a2 = red[fp + 128], a3 = red[fp + 192];
        float2 o;
        o.x = (a0.x + a1.x) + (a2.x + a3.x);
        o.y = (a0.y + a1.y) + (a2.y + a3.y);
        *(float2*)&part[(size_t)blockIdx.x * DF + fp * 2] = o;
    }
}

__global__ __launch_bounds__(128) void k_poolB(const float* __restrict__ part,
                                               const int* __restrict__ gstart,
                                               float* __restrict__ pooled) {
    int g = blockIdx.x;
    int f = threadIdx.x;
    float s = 0.f;
#pragma unroll
    for (int c = 0; c < PCH; c++) s += part[(size_t)(g * PCH + c) * DF + f];
    int cnt = gstart[g + 1] - gstart[g];
    pooled[g * DF + phi(f)] = s / (float)max(cnt, 1);
}

__global__ __launch_bounds__(64) void k_fc(const float* __restrict__ pooled,
                                           const float* __restrict__ Wfc,
                                           const float* __restrict__ bfc,
                                           float* __restrict__ out) {
    int g = blockIdx.x;
    int o = threadIdx.x;
    float acc = bfc[o];
    for (int k = 0; k < DF; k++) acc += pooled[g * DF + k] * Wfc[k * DOUT + o];
    out[g * DOUT + o] = acc;
}

// ---------------- launch ----------------

extern "C" void kernel_launch(void* const* d_in, const int* in_sizes, int n_in,
                              void* d_out, int out_size, void* d_ws, size_t ws_size,
                              hipStream_t stream) {
    const float* x     = (const float*)d_in[0];
    const int*   ei    = (const int*)d_in[1];
    const int*   batch = (const int*)d_in[2];
    const float* W1 = (const float*)d_in[3];
    const float* b1 = (const float*)d_in[4];
    const float* W2 = (const float*)d_in[5];
    const float* b2 = (const float*)d_in[6];
    const float* W3 = (const float*)d_in[7];
    const float* b3 = (const float*)d_in[8];
    const float* Wfc = (const float*)d_in[9];
    const float* bfc = (const float*)d_in[10];
    float* out = (float*)d_out;

    char* p = (char*)d_ws;
    unsigned short* xb = (unsigned short*)p;  p += (size_t)NN * DF * sizeof(short);
    unsigned short* hs = (unsigned short*)p;  p += (size_t)NN * DF * sizeof(short);
    unsigned short* ob = (unsigned short*)p;  p += (size_t)NN * DF * sizeof(short);
    unsigned char*  fs8 = (unsigned char*)p;  p += (size_t)NN * DF;
    unsigned short* Wb1 = (unsigned short*)p; p += 16384 * sizeof(short);
    unsigned short* Wb2 = (unsigned short*)p; p += 16384 * sizeof(short);
    unsigned short* Wb3 = (unsigned short*)p; p += 16384 * sizeof(short);
    float* dinv = (float*)p;           p += (size_t)NN * sizeof(float);
    int* rowptr = (int*)p;             p += (size_t)(NN + 4) * sizeof(int);
    int* col    = (int*)p;             p += (size_t)NE * sizeof(int);
    int2* ebuf  = (int2*)p;            p += (size_t)NE * sizeof(int2);
    int* bhist  = (int*)p;             p += (size_t)(NB + 4) * sizeof(int);
    int* bbase  = (int*)p;             p += (size_t)(NB + 4) * sizeof(int);
    int* bcur   = (int*)p;             p += (size_t)(NB + 4) * sizeof(int);
    int* gstart = (int*)p;             p += (size_t)(NG + 4) * sizeof(int);
    float* pooled = (float*)p;         p += (size_t)NG * DF * sizeof(float);
    float* part  = (float*)p;          p += (size_t)NG * PCH * DF * sizeof(float);

    const int* e_src = ei;
    const int* e_dst = ei + NE;

    // CSR build + graph bounds
    k_init<<<3, 256, 0, stream>>>(bhist, batch, gstart);
    k_bcount<<<NBLKA, 256, 0, stream>>>(e_dst, bhist);
    k_bscan<<<1, 512, 0, stream>>>(bhist, bbase, bcur);
    k_pairs<<<NBLKA, 256, 0, stream>>>(e_src, e_dst, bcur, ebuf);
    k_build<<<NB, 256, 0, stream>>>(ebuf, bbase, rowptr, dinv, col);

    // bf16 conversions
    k_prepw<<<dim3(8, 3), 256, 0, stream>>>(W1, W2, W3, Wb1, Wb2, Wb3);
    k_prepx<<<(NN * DF / 8 + 255) / 256, 256, 0, stream>>>(x, xb);

    int ggrid = (NN + 63) / 64;
    int agg_blocks = (NN + 3) / 4;   // NN divisible by 4: every wave owns a node

    // layer 1
    k_gemm<<<ggrid, 256, 0, stream>>>(xb, Wb1, dinv, hs, fs8);
    k_agg<<<agg_blocks, 256, 0, stream>>>(hs, fs8, rowptr, col, dinv, b1, ob);
    // layer 2
    k_gemm<<<ggrid, 256, 0, stream>>>(ob, Wb2, dinv, hs, fs8);
    k_agg<<<agg_blocks, 256, 0, stream>>>(hs, fs8, rowptr, col, dinv, b2, ob);
    // layer 3
    k_gemm<<<ggrid, 256, 0, stream>>>(ob, Wb3, dinv, hs, fs8);
    k_agg<<<agg_blocks, 256, 0, stream>>>(hs, fs8, rowptr, col, dinv, b3, ob);

    // pool + fc
    k_poolA<<<NG * PCH, 256, 0, stream>>>(ob, gstart, part);
    k_poolB<<<NG, 128, 0, stream>>>(part, gstart, pooled);
    k_fc<<<NG, 64, 0, stream>>>(pooled, Wfc, bfc, out);
}